// Round 4
// baseline (107.856 us; speedup 1.0000x reference)
//
#include <hip/hip_runtime.h>
#include <hip/hip_bf16.h>

typedef __bf16 bf16_t;
typedef __attribute__((ext_vector_type(8))) __bf16 bf16x8;
typedef __attribute__((ext_vector_type(4))) float f32x4;

#define KDIM 1152
#define NDIM 1152
#define BM 256
#define BN 144
#define BK 32
#define NKT 36
#define NT 8                    /* 1152/144 n-tiles */
#define KT_BYTES 9216           /* 9 ngrp * 4 khalf * 16 nrow * 16B */
#define TILE_BYTES (NKT * KT_BYTES)

__device__ __forceinline__ void gload_lds16(const void* g, void* l) {
    __builtin_amdgcn_global_load_lds(
        (const __attribute__((address_space(1))) void*)g,
        (__attribute__((address_space(3))) void*)l, 16, 0, 0);
}

// Weff panel in fragment-contiguous order per n-tile:
//  byte(n,k) = tile*TILE_BYTES + (k>>5)*9216 + (nin>>4)*1024 + ((k>>3)&3)*256
//              + (nin&15)*16 + (k&7)*2      (tile = n/144, nin = n%144)
// => GEMM stages each 9KB k-slab with linear gload_lds and reads frags at
//    ngrp*1024 + lane*16 (contiguous 1KB per read: zero bank conflicts).
__global__ void build_wb(const float* __restrict__ W,
                         const float* __restrict__ bvec,
                         bf16_t* __restrict__ Bm,
                         float* __restrict__ bias)
{
    const int t = blockIdx.x * blockDim.x + threadIdx.x;
    if (t < NDIM) {
        const int o = t / 9, p = t - o * 9;
        bias[t] = bvec[p * 128 + o];
    }
    const int c = t & 127;
    const int o = (t >> 7) & 127;
    const int p = t >> 14;
    if (p >= 9) return;
    const int r = p / 3, cc = p - r * 3;
    float eff[3][3] = {{0.f,0.f,0.f},{0.f,0.f,0.f},{0.f,0.f,0.f}};
    const float* w = W + (size_t)((p * 128 + o) * 128 + c) * 9;
    #pragma unroll
    for (int i = 0; i < 3; ++i) {
        const int a = (2 + r + i) / 3;
        #pragma unroll
        for (int j = 0; j < 3; ++j) {
            const int bb = (2 + cc + j) / 3;
            eff[a][bb] += w[i * 3 + j];
        }
    }
    const int n = o * 9 + p;
    const int tile = n / 144;
    const int nin = n - tile * 144;
    #pragma unroll
    for (int a = 0; a < 3; ++a)
        #pragma unroll
        for (int bb = 0; bb < 3; ++bb) {
            const int k = c * 9 + a * 3 + bb;
            const size_t idx = (size_t)tile * (TILE_BYTES / 2)
                             + (k >> 5) * 4608 + (nin >> 4) * 512
                             + ((k >> 3) & 3) * 128 + (nin & 15) * 8 + (k & 7);
            Bm[idx] = (bf16_t)eff[a][bb];
        }
}

// out[16384,1152] = X(fp32->bf16 in-reg) * Weff(bf16) + bias.
// BM=256 x BN=144, BK=32, 4 waves (4m x 1n): wave owns 64 rows -> A frags
// loaded global->reg directly (no LDS for A). B double-buffered in LDS via
// gload_lds; counted vmcnt (never 0 in loop) + raw s_barrier.
__launch_bounds__(256, 2)
__global__ void ind_gemm(const float* __restrict__ X,
                         const bf16_t* __restrict__ Bm,
                         const float* __restrict__ bias,
                         float* __restrict__ out)
{
    __shared__ char Bs[2][KT_BYTES];
    __shared__ char Scr[1024];          // dummy gld sink (keeps vmcnt uniform)

    const int tid = threadIdx.x;
    const int lane = tid & 63;
    const int w = tid >> 6;

    // XCD swizzle: 512 blocks, consecutive swz share an m-panel across 8 n-tiles
    const int bid = blockIdx.x;
    const int swz = (bid & 7) * 64 + (bid >> 3);
    const int mt = swz >> 3;
    const int nt = swz & 7;
    const int m0 = mt * BM;

    // A frag addressing: row = m0 + w*64 + mi*16 + (lane&15); k0 = (lane>>4)*8
    const float* abase = X + (size_t)(m0 + w * 64 + (lane & 15)) * KDIM
                           + ((lane >> 4) * 8);
    const char* bpanel = (const char*)Bm + (size_t)nt * TILE_BYTES;

    f32x4 acc[4][9];
    #pragma unroll
    for (int i = 0; i < 4; ++i)
        #pragma unroll
        for (int j = 0; j < 9; ++j)
            acc[i][j] = (f32x4){0.f, 0.f, 0.f, 0.f};

    f32x4 ra[4][2];
    bf16x8 af[4];

    #define LOADA(KT) do {                                                  \
        _Pragma("unroll")                                                   \
        for (int mi = 0; mi < 4; ++mi) {                                    \
            const float* p_ = abase + (size_t)mi * 16 * KDIM + (KT) * BK;   \
            asm volatile("global_load_dwordx4 %0, %2, off\n\t"              \
                         "global_load_dwordx4 %1, %2, off offset:16"        \
                         : "=&v"(ra[mi][0]), "=&v"(ra[mi][1])               \
                         : "v"(p_) : "memory");                             \
        } } while (0)

    #define GLDB(KT, BUF) do {                                              \
        const char* src_ = bpanel + (size_t)(KT) * KT_BYTES + lane * 16;    \
        _Pragma("unroll")                                                   \
        for (int q_ = 0; q_ < 3; ++q_) {                                    \
            const int idx_ = w * 3 + q_;                                    \
            if (idx_ < 9) gload_lds16(src_ + idx_ * 1024, &Bs[BUF][idx_ * 1024]); \
            else          gload_lds16(bpanel + lane * 16, Scr);             \
        } } while (0)

    #define CVT() do {                                                      \
        _Pragma("unroll")                                                   \
        for (int mi = 0; mi < 4; ++mi) {                                    \
            bf16x8 v_;                                                      \
            _Pragma("unroll")                                               \
            for (int j_ = 0; j_ < 4; ++j_) {                                \
                v_[j_]     = (__bf16)ra[mi][0][j_];                         \
                v_[4 + j_] = (__bf16)ra[mi][1][j_];                         \
            }                                                               \
            af[mi] = v_;                                                    \
        } } while (0)

    #define COMPUTE(BUF) do {                                               \
        const char* Bb_ = &Bs[BUF][0];                                      \
        __builtin_amdgcn_s_setprio(1);                                      \
        _Pragma("unroll")                                                   \
        for (int c_ = 0; c_ < 3; ++c_) {                                    \
            bf16x8 bfr_[3];                                                 \
            _Pragma("unroll")                                               \
            for (int j_ = 0; j_ < 3; ++j_)                                  \
                bfr_[j_] = *(const bf16x8*)(Bb_ + (c_ * 3 + j_) * 1024 + lane * 16); \
            _Pragma("unroll")                                               \
            for (int mi = 0; mi < 4; ++mi)                                  \
                _Pragma("unroll")                                           \
                for (int j_ = 0; j_ < 3; ++j_)                              \
                    acc[mi][c_ * 3 + j_] = __builtin_amdgcn_mfma_f32_16x16x32_bf16( \
                        af[mi], bfr_[j_], acc[mi][c_ * 3 + j_], 0, 0, 0);   \
        }                                                                   \
        __builtin_amdgcn_s_setprio(0);                                      \
    } while (0)

    // ---- prologue: B(0) staged, A(0) in flight ----
    GLDB(0, 0);
    LOADA(0);
    asm volatile("s_waitcnt vmcnt(8)" ::: "memory");  // drain B(0); A(0) flies
    __builtin_amdgcn_sched_barrier(0);
    __builtin_amdgcn_s_barrier();

    #pragma unroll 1
    for (int t = 0; t < NKT - 1; ++t) {
        const int buf = t & 1;
        GLDB(t + 1, buf ^ 1);                         // outstanding: A(t)8 + B(t+1)3
        asm volatile("s_waitcnt vmcnt(3)" ::: "memory"); // A(t) regs ready
        __builtin_amdgcn_sched_barrier(0);
        CVT();                                        // frees ra
        LOADA(t + 1);                                 // outstanding: B(t+1)3 + A(t+1)8
        COMPUTE(buf);
        asm volatile("s_waitcnt vmcnt(8) lgkmcnt(0)" ::: "memory"); // drain B(t+1)
        __builtin_amdgcn_sched_barrier(0);
        __builtin_amdgcn_s_barrier();
    }
    // ---- final K-step ----
    asm volatile("s_waitcnt vmcnt(0)" ::: "memory");
    __builtin_amdgcn_sched_barrier(0);
    CVT();
    COMPUTE((NKT - 1) & 1);

    #undef LOADA
    #undef GLDB
    #undef CVT
    #undef COMPUTE

    // ---- epilogue: C/D col=lane&15, row=(lane>>4)*4+reg ----
    const int orow = (lane >> 4) * 4;
    const int ocol = lane & 15;
    const int gn0 = nt * BN + ocol;
    #pragma unroll
    for (int ni = 0; ni < 9; ++ni) {
        const float bv = bias[gn0 + ni * 16];
        #pragma unroll
        for (int mi = 0; mi < 4; ++mi) {
            float* po = out + (size_t)(m0 + w * 64 + mi * 16 + orow) * NDIM
                            + gn0 + ni * 16;
            #pragma unroll
            for (int r = 0; r < 4; ++r)
                po[(size_t)r * NDIM] = acc[mi][ni][r] + bv;
        }
    }
}

extern "C" void kernel_launch(void* const* d_in, const int* in_sizes, int n_in,
                              void* d_out, int out_size, void* d_ws, size_t ws_size,
                              hipStream_t stream)
{
    const float* x  = (const float*)d_in[0];
    const float* W  = (const float*)d_in[1];
    const float* bv = (const float*)d_in[2];
    float* out = (float*)d_out;

    bf16_t* Bm  = (bf16_t*)d_ws;                              // 1152*1152 bf16 = 2.65 MB
    float* bias = (float*)((char*)d_ws + (size_t)KDIM * NDIM * sizeof(bf16_t));

    build_wb<<<576, 256, 0, stream>>>(W, bv, Bm, bias);
    ind_gemm<<<512, 256, 0, stream>>>(x, Bm, bias, out);
}

// Round 5
// 94.736 us; speedup vs baseline: 1.1385x; 1.1385x over previous
//
#include <hip/hip_runtime.h>
#include <hip/hip_bf16.h>

typedef __bf16 bf16_t;
typedef __attribute__((ext_vector_type(8))) __bf16 bf16x8;
typedef __attribute__((ext_vector_type(4))) float f32x4;

#define KDIM 1152
#define NDIM 1152
#define BM 128
#define BN 192
#define BK 32
#define NKT 36
#define NTILES 6                      /* 1152/192 */
#define SLAB_BYTES 12288              /* BN*BK*2 = 768 x 16B units */
#define TILE_BYTES (NKT * SLAB_BYTES) /* 442368 B per n-tile */

__device__ __forceinline__ void gload_lds16(const void* g, void* l) {
    __builtin_amdgcn_global_load_lds(
        (const __attribute__((address_space(1))) void*)g,
        (__attribute__((address_space(3))) void*)l, 16, 0, 0);
}

// Weff panel, fragment-contiguous per n-tile (BN=192):
//   bf16 idx(n,k) = tile*221184 + (k>>5)*6144 + (nin>>4)*512 + ((k>>3)&3)*128
//                   + (nin&15)*8 + (k&7)     (tile = n/192, nin = n%192)
// => GEMM stages each 12 KB k-slab linearly (768 units = 3 rounds x 256 thr)
//    and reads frags at ngrp*1024 + (lane>>4)*256 + (lane&15)*16: 1 KB
//    contiguous per wave read -> zero bank conflicts.
__global__ void build_wb(const float* __restrict__ W,
                         const float* __restrict__ bvec,
                         bf16_t* __restrict__ Bm,
                         float* __restrict__ bias)
{
    const int t = blockIdx.x * blockDim.x + threadIdx.x;
    if (t < NDIM) {
        const int o = t / 9, p = t - o * 9;
        bias[t] = bvec[p * 128 + o];
    }
    const int c = t & 127;
    const int o = (t >> 7) & 127;
    const int p = t >> 14;
    if (p >= 9) return;
    const int r = p / 3, cc = p - r * 3;
    float eff[3][3] = {{0.f,0.f,0.f},{0.f,0.f,0.f},{0.f,0.f,0.f}};
    const float* w = W + (size_t)((p * 128 + o) * 128 + c) * 9;
    #pragma unroll
    for (int i = 0; i < 3; ++i) {
        const int a = (2 + r + i) / 3;
        #pragma unroll
        for (int j = 0; j < 3; ++j) {
            const int bb = (2 + cc + j) / 3;
            eff[a][bb] += w[i * 3 + j];
        }
    }
    const int n = o * 9 + p;
    const int tile = n / BN;
    const int nin = n - tile * BN;
    #pragma unroll
    for (int a = 0; a < 3; ++a)
        #pragma unroll
        for (int bb = 0; bb < 3; ++bb) {
            const int k = c * 9 + a * 3 + bb;
            const size_t idx = (size_t)tile * (TILE_BYTES / 2)
                             + (k >> 5) * (SLAB_BYTES / 2)
                             + (nin >> 4) * 512 + ((k >> 3) & 3) * 128
                             + (nin & 15) * 8 + (k & 7);
            Bm[idx] = (bf16_t)eff[a][bb];
        }
}

// out[16384,1152] = X(fp32->bf16 in-reg) * Weff(bf16) + bias.
// BM=128 x BN=192, BK=32, 4 waves (wave = 32 rows x 192 cols, acc 2x12 frags
// = 96 VGPR). A: global->reg (no LDS). B: LDS dbuf via linear gload_lds.
// Counted vmcnt (never 0 in main loop) + raw s_barrier. 3 blocks/CU,
// grid 768 = machine-filling exactly.
__launch_bounds__(256, 3)
__global__ void ind_gemm(const float* __restrict__ X,
                         const bf16_t* __restrict__ Bm,
                         const float* __restrict__ bias,
                         float* __restrict__ out)
{
    __shared__ char Bs[2][SLAB_BYTES];

    const int tid = threadIdx.x;
    const int lane = tid & 63;
    const int w = tid >> 6;

    // XCD swizzle: 768 blocks, 96/XCD; consecutive swz share an m-panel
    // across the 6 n-tiles (L2 reuse of X).
    const int bid = blockIdx.x;
    const int swz = (bid & 7) * 96 + (bid >> 3);
    const int mt = swz / NTILES;
    const int nt = swz - mt * NTILES;
    const int m0 = mt * BM;

    // A frags: row = m0 + w*32 + mi*16 + (lane&15); k0 = (lane>>4)*8
    const float* abase = X + (size_t)(m0 + w * 32 + (lane & 15)) * KDIM
                           + ((lane >> 4) * 8);
    const char* bpanel = (const char*)Bm + (size_t)nt * TILE_BYTES;
    const int fr = (lane >> 4) * 256 + (lane & 15) * 16;

    f32x4 acc[2][12];
    #pragma unroll
    for (int i = 0; i < 2; ++i)
        #pragma unroll
        for (int j = 0; j < 12; ++j)
            acc[i][j] = (f32x4){0.f, 0.f, 0.f, 0.f};

    f32x4 ra[2][2];
    bf16x8 af[2];

    #define LOADA(KT) do {                                                  \
        _Pragma("unroll")                                                   \
        for (int mi = 0; mi < 2; ++mi) {                                    \
            const float* p_ = abase + (size_t)mi * 16 * KDIM + (KT) * BK;   \
            asm volatile("global_load_dwordx4 %0, %2, off\n\t"              \
                         "global_load_dwordx4 %1, %2, off offset:16"        \
                         : "=&v"(ra[mi][0]), "=&v"(ra[mi][1])               \
                         : "v"(p_) : "memory");                             \
        } } while (0)

    #define GLDB(KT, BUF) do {                                              \
        const char* src_ = bpanel + (size_t)(KT) * SLAB_BYTES;              \
        _Pragma("unroll")                                                   \
        for (int r_ = 0; r_ < 3; ++r_) {                                    \
            const int u_ = (tid + r_ * 256) * 16;                           \
            gload_lds16(src_ + u_, &Bs[BUF][u_]);                           \
        } } while (0)

    #define CVT() do {                                                      \
        _Pragma("unroll")                                                   \
        for (int mi = 0; mi < 2; ++mi) {                                    \
            bf16x8 v_;                                                      \
            _Pragma("unroll")                                               \
            for (int j_ = 0; j_ < 4; ++j_) {                                \
                v_[j_]     = (__bf16)ra[mi][0][j_];                         \
                v_[4 + j_] = (__bf16)ra[mi][1][j_];                         \
            }                                                               \
            af[mi] = v_;                                                    \
        } } while (0)

    #define COMPUTE(BUF) do {                                               \
        const char* Bb_ = &Bs[BUF][0];                                      \
        __builtin_amdgcn_s_setprio(1);                                      \
        _Pragma("unroll")                                                   \
        for (int c_ = 0; c_ < 4; ++c_) {                                    \
            bf16x8 bfr_[3];                                                 \
            _Pragma("unroll")                                               \
            for (int j_ = 0; j_ < 3; ++j_)                                  \
                bfr_[j_] = *(const bf16x8*)(Bb_ + (c_ * 3 + j_) * 1024 + fr); \
            _Pragma("unroll")                                               \
            for (int mi = 0; mi < 2; ++mi)                                  \
                _Pragma("unroll")                                           \
                for (int j_ = 0; j_ < 3; ++j_)                              \
                    acc[mi][c_ * 3 + j_] = __builtin_amdgcn_mfma_f32_16x16x32_bf16( \
                        af[mi], bfr_[j_], acc[mi][c_ * 3 + j_], 0, 0, 0);   \
        }                                                                   \
        __builtin_amdgcn_s_setprio(0);                                      \
    } while (0)

    // ---- prologue: B(0)[3] + A(0)[4] in flight; drain B(0) only ----
    GLDB(0, 0);
    LOADA(0);
    asm volatile("s_waitcnt vmcnt(4)" ::: "memory");
    __builtin_amdgcn_sched_barrier(0);
    __builtin_amdgcn_s_barrier();

    #pragma unroll 1
    for (int t = 0; t < NKT - 1; ++t) {
        const int buf = t & 1;
        GLDB(t + 1, buf ^ 1);                            // out: A(t)4 + B(t+1)3
        asm volatile("s_waitcnt vmcnt(3)" ::: "memory"); // drain A(t)
        __builtin_amdgcn_sched_barrier(0);
        CVT();                                           // frees ra
        LOADA(t + 1);                                    // out: B(t+1)3 + A(t+1)4
        COMPUTE(buf);
        asm volatile("s_waitcnt vmcnt(4) lgkmcnt(0)" ::: "memory"); // drain B(t+1)
        __builtin_amdgcn_sched_barrier(0);
        __builtin_amdgcn_s_barrier();
    }
    // ---- final K-step ----
    asm volatile("s_waitcnt vmcnt(0)" ::: "memory");
    __builtin_amdgcn_sched_barrier(0);
    CVT();
    COMPUTE((NKT - 1) & 1);

    #undef LOADA
    #undef GLDB
    #undef CVT
    #undef COMPUTE

    // ---- epilogue: C/D col=lane&15, row=(lane>>4)*4+reg ----
    const int orow = (lane >> 4) * 4;
    const int ocol = lane & 15;
    const int gn0 = nt * BN + ocol;
    #pragma unroll
    for (int ni = 0; ni < 12; ++ni) {
        const float bv = bias[gn0 + ni * 16];
        #pragma unroll
        for (int mi = 0; mi < 2; ++mi) {
            float* po = out + (size_t)(m0 + w * 32 + mi * 16 + orow) * NDIM
                            + gn0 + ni * 16;
            #pragma unroll
            for (int r = 0; r < 4; ++r)
                po[(size_t)r * NDIM] = acc[mi][ni][r] + bv;
        }
    }
}

extern "C" void kernel_launch(void* const* d_in, const int* in_sizes, int n_in,
                              void* d_out, int out_size, void* d_ws, size_t ws_size,
                              hipStream_t stream)
{
    const float* x  = (const float*)d_in[0];
    const float* W  = (const float*)d_in[1];
    const float* bv = (const float*)d_in[2];
    float* out = (float*)d_out;

    bf16_t* Bm  = (bf16_t*)d_ws;                              // 1152*1152 bf16 = 2.65 MB
    float* bias = (float*)((char*)d_ws + (size_t)KDIM * NDIM * sizeof(bf16_t));

    build_wb<<<576, 256, 0, stream>>>(W, bv, Bm, bias);
    ind_gemm<<<768, 256, 0, stream>>>(x, Bm, bias, out);
}